// Round 1
// baseline (10420.153 us; speedup 1.0000x reference)
//
#include <hip/hip_runtime.h>

// Problem constants
#define B_ 64
#define T_ 512
#define DIN_ 256
#define N_ 1024
#define O_ 128

using half8 = __attribute__((ext_vector_type(8))) _Float16;
using f32x4 = __attribute__((ext_vector_type(4))) float;

__device__ __forceinline__ half8 cvt8(float4 a, float4 b) {
    half8 h;
    h[0] = (_Float16)a.x; h[1] = (_Float16)a.y; h[2] = (_Float16)a.z; h[3] = (_Float16)a.w;
    h[4] = (_Float16)b.x; h[5] = (_Float16)b.y; h[6] = (_Float16)b.z; h[7] = (_Float16)b.w;
    return h;
}

__device__ __forceinline__ float fast_tanh(float x) {
    float ax = __builtin_fabsf(x);
    float e  = __expf(-2.0f * ax);            // exp(-2|x|) in (0,1]
    float r  = __fdividef(1.0f - e, 1.0f + e); // tanh(|x|)
    return x < 0.0f ? -r : r;
}

// ---------------------------------------------------------------------------
// Init: zero the barrier counter (ws is poisoned 0xAA before every launch)
// ---------------------------------------------------------------------------
__global__ void init_kernel(unsigned int* cnt) {
    if (threadIdx.x == 0) cnt[0] = 0u;
}

// ---------------------------------------------------------------------------
// Persistent recurrence kernel: 64 blocks x 256 threads.
// Block j owns columns [16j, 16j+16). Wave w owns batch rows [16w, 16w+16).
// W column-slab (fp16 B-fragments, 128 VGPRs) + Win slab (32 VGPRs) are held
// in registers for the whole kernel. u_{t+1} = x_t @ Win is computed during
// step t and carried in registers (same C/D layout -> seeds next accumulator).
// Grid barrier: monotonic atomic counter, device-scope fences.
// ---------------------------------------------------------------------------
__global__ __launch_bounds__(256, 1) void rnn_kernel(
    const float* __restrict__ X,    // [B][T][DIN]
    const float* __restrict__ W,    // [N][N] (k-major rows)
    const float* __restrict__ Win,  // [DIN][N]
    float* __restrict__ s_out,      // [B][T][N]
    _Float16* __restrict__ s_exch,  // [2][B][N] fp16 ping-pong
    unsigned int* __restrict__ cnt)
{
    const int n0   = blockIdx.x * 16;
    const int tid  = threadIdx.x;
    const int wave = tid >> 6;
    const int lane = tid & 63;
    const int l15  = lane & 15;
    const int quad = lane >> 4;
    const int arow = wave * 16 + l15;        // A-fragment row (batch b)
    const int crow = wave * 16 + quad * 4;   // C/D base row   (batch b)

    __shared__ _Float16 Wt[16][1032];   // W^T slab, padded (row = 2064 B, 16B-aligned)
    __shared__ _Float16 WinT[16][264];  // Win^T slab, padded

    // ---- one-time staging: W[:, n0:n0+16] and Win[:, n0:n0+16] -> LDS (transposed)
    {
        const int c = tid & 15, k0 = tid >> 4;
        #pragma unroll 4
        for (int k = k0; k < N_; k += 16)
            Wt[c][k] = (_Float16)W[(size_t)k * N_ + n0 + c];
        for (int k = k0; k < DIN_; k += 16)
            WinT[c][k] = (_Float16)Win[(size_t)k * N_ + n0 + c];
    }
    __syncthreads();

    // ---- B-fragments into registers (held across all 511 steps)
    half8 wf[32];
    #pragma unroll
    for (int kb = 0; kb < 32; ++kb)
        wf[kb] = *(const half8*)&Wt[l15][kb * 32 + quad * 8];
    half8 winf[8];
    #pragma unroll
    for (int kb = 0; kb < 8; ++kb)
        winf[kb] = *(const half8*)&WinT[l15][kb * 32 + quad * 8];

    // ---- s[:, 0, :] = 0
    #pragma unroll
    for (int r = 0; r < 4; ++r)
        s_out[(size_t)(crow + r) * T_ * N_ + n0 + l15] = 0.0f;

    // ---- u_1 = X[:,0,:] @ Win
    f32x4 u = {0.f, 0.f, 0.f, 0.f};
    {
        const float* xp = X + (size_t)arow * T_ * DIN_ + quad * 8;
        #pragma unroll
        for (int kb = 0; kb < 8; ++kb) {
            float4 x0 = *(const float4*)(xp + kb * 32);
            float4 x1 = *(const float4*)(xp + kb * 32 + 4);
            u = __builtin_amdgcn_mfma_f32_16x16x32_f16(cvt8(x0, x1), winf[kb], u, 0, 0, 0);
        }
    }

    for (int t = 1; t < T_; ++t) {
        // prefetch X[:, t, :] for u_{t+1} (independent of barrier)
        float4 xpre[16];
        if (t < T_ - 1) {
            const float* xp = X + ((size_t)arow * T_ + t) * DIN_ + quad * 8;
            #pragma unroll
            for (int kb = 0; kb < 8; ++kb) {
                xpre[2 * kb]     = *(const float4*)(xp + kb * 32);
                xpre[2 * kb + 1] = *(const float4*)(xp + kb * 32 + 4);
            }
        }

        f32x4 acc[4];
        acc[0] = u;
        acc[1] = f32x4{0.f, 0.f, 0.f, 0.f};
        acc[2] = f32x4{0.f, 0.f, 0.f, 0.f};
        acc[3] = f32x4{0.f, 0.f, 0.f, 0.f};

        if (t >= 2) {
            // wait for all 64 blocks to have published s_{t-1}
            if (tid == 0) {
                const unsigned int target = (unsigned int)(t - 1) * 64u;
                while (__hip_atomic_load(cnt, __ATOMIC_ACQUIRE, __HIP_MEMORY_SCOPE_AGENT) < target)
                    __builtin_amdgcn_s_sleep(1);
            }
            __syncthreads();
            __threadfence();  // acquire: invalidate stale L1/L2 before reading s_{t-1}

            const _Float16* sb = s_exch + (size_t)((t - 1) & 1) * (B_ * N_)
                               + (size_t)arow * N_ + quad * 8;
            #pragma unroll
            for (int kb = 0; kb < 32; ++kb) {
                half8 a = *(const half8*)(sb + kb * 32);
                acc[kb & 3] = __builtin_amdgcn_mfma_f32_16x16x32_f16(a, wf[kb], acc[kb & 3], 0, 0, 0);
            }
        }

        // u_{t+1} = X[:,t,:] @ Win  (independent MFMA chain)
        f32x4 un = {0.f, 0.f, 0.f, 0.f};
        if (t < T_ - 1) {
            #pragma unroll
            for (int kb = 0; kb < 8; ++kb)
                un = __builtin_amdgcn_mfma_f32_16x16x32_f16(
                        cvt8(xpre[2 * kb], xpre[2 * kb + 1]), winf[kb], un, 0, 0, 0);
        }

        f32x4 z;
        #pragma unroll
        for (int r = 0; r < 4; ++r) z[r] = acc[0][r] + acc[1][r] + acc[2][r] + acc[3][r];

        float*     so = s_out  + (size_t)crow * T_ * N_ + (size_t)t * N_ + n0 + l15;
        _Float16*  se = s_exch + (size_t)(t & 1) * (B_ * N_) + (size_t)crow * N_ + n0 + l15;
        #pragma unroll
        for (int r = 0; r < 4; ++r) {
            float v = fast_tanh(z[r]);
            so[(size_t)r * T_ * N_] = v;
            se[r * N_] = (_Float16)v;
        }
        u = un;

        __threadfence();   // release: publish s_t before signalling
        __syncthreads();
        if (tid == 0)
            __hip_atomic_fetch_add(cnt, 1u, __ATOMIC_RELEASE, __HIP_MEMORY_SCOPE_AGENT);
    }
}

// ---------------------------------------------------------------------------
// Epilogue: out = s @ Wout + bout.  M=32768, N=128, K=1024.
// 512 blocks x 256 threads; block tile 64(M) x 128(N); per-K-chunk Wout
// staged fp16-transposed in LDS.
// ---------------------------------------------------------------------------
__global__ __launch_bounds__(256, 2) void out_gemm(
    const float* __restrict__ s_in,   // [B*T][N] fp32
    const float* __restrict__ Wout,   // [N][O]
    const float* __restrict__ bout,   // [O]
    float* __restrict__ outp)         // [B*T][O]
{
    const int m0   = blockIdx.x * 64;
    const int tid  = threadIdx.x;
    const int wave = tid >> 6;
    const int lane = tid & 63;
    const int l15  = lane & 15;
    const int quad = lane >> 4;

    __shared__ _Float16 WoT[128][56];   // row stride 112 B (16B-aligned)

    f32x4 acc[8];
    #pragma unroll
    for (int nt = 0; nt < 8; ++nt) acc[nt] = f32x4{0.f, 0.f, 0.f, 0.f};
    float bv[8];
    #pragma unroll
    for (int nt = 0; nt < 8; ++nt) bv[nt] = bout[nt * 16 + l15];

    for (int kb = 0; kb < 32; ++kb) {
        __syncthreads();
        for (int i = tid; i < 32 * 128; i += 256) {
            int c = i & 127, kk = i >> 7;
            WoT[c][kk] = (_Float16)Wout[(size_t)(kb * 32 + kk) * O_ + c];
        }
        __syncthreads();

        const float* ap = s_in + (size_t)(m0 + wave * 16 + l15) * N_ + kb * 32 + quad * 8;
        float4 a0 = *(const float4*)ap;
        float4 a1 = *(const float4*)(ap + 4);
        half8 a = cvt8(a0, a1);
        #pragma unroll
        for (int nt = 0; nt < 8; ++nt) {
            half8 b = *(const half8*)&WoT[nt * 16 + l15][quad * 8];
            acc[nt] = __builtin_amdgcn_mfma_f32_16x16x32_f16(a, b, acc[nt], 0, 0, 0);
        }
    }

    float* op = outp + (size_t)(m0 + wave * 16 + quad * 4) * O_ + l15;
    #pragma unroll
    for (int nt = 0; nt < 8; ++nt)
        #pragma unroll
        for (int r = 0; r < 4; ++r)
            op[(size_t)r * O_ + nt * 16] = acc[nt][r] + bv[nt];
}

extern "C" void kernel_launch(void* const* d_in, const int* in_sizes, int n_in,
                              void* d_out, int out_size, void* d_ws, size_t ws_size,
                              hipStream_t stream) {
    const float* X    = (const float*)d_in[0];   // [64][512][256]
    const float* Win  = (const float*)d_in[1];   // [256][1024]
    const float* W    = (const float*)d_in[2];   // [1024][1024]
    const float* Wout = (const float*)d_in[3];   // [1024][128]
    const float* bout = (const float*)d_in[4];   // [128]

    float* s_out = (float*)d_out;                          // [64][512][1024]
    float* outp  = s_out + (size_t)B_ * T_ * N_;           // [64][512][128]

    unsigned int* cnt = (unsigned int*)d_ws;
    _Float16* s_exch  = (_Float16*)((char*)d_ws + 1024);   // 2 * 64*1024 fp16 = 256 KB

    init_kernel<<<1, 64, 0, stream>>>(cnt);
    rnn_kernel<<<64, 256, 0, stream>>>(X, W, Win, s_out, s_exch, cnt);
    out_gemm<<<512, 256, 0, stream>>>(s_out, Wout, bout, outp);
}

// Round 2
// 6039.861 us; speedup vs baseline: 1.7252x; 1.7252x over previous
//
#include <hip/hip_runtime.h>

// Problem constants
#define B_ 64
#define T_ 512
#define DIN_ 256
#define N_ 1024
#define O_ 128

using half8 = __attribute__((ext_vector_type(8))) _Float16;
using f32x4 = __attribute__((ext_vector_type(4))) float;

__device__ __forceinline__ half8 cvt8(float4 a, float4 b) {
    half8 h;
    h[0] = (_Float16)a.x; h[1] = (_Float16)a.y; h[2] = (_Float16)a.z; h[3] = (_Float16)a.w;
    h[4] = (_Float16)b.x; h[5] = (_Float16)b.y; h[6] = (_Float16)b.z; h[7] = (_Float16)b.w;
    return h;
}

__device__ __forceinline__ float fast_tanh(float x) {
    float ax = __builtin_fabsf(x);
    float e  = __expf(-2.0f * ax);
    float r  = __fdividef(1.0f - e, 1.0f + e);
    return x < 0.0f ? -r : r;
}

// ---------------------------------------------------------------------------
// Init: zero the 4 group counters (ws poisoned 0xAA before every launch)
// ---------------------------------------------------------------------------
__global__ void init_kernel(unsigned int* cnt) {
    if (threadIdx.x < 4) cnt[threadIdx.x * 32] = 0u;
}

// ---------------------------------------------------------------------------
// Persistent recurrence: 64 blocks = 4 batch-slabs (bs) x 16 col-groups (cg).
// Block = 16 batch rows x 64 cols; wave w owns cols cg*64+w*16..+16 with its
// W column-slab (128 VGPRs fp16) + Win slab (32 VGPRs) register-resident.
// Sync: 4 independent groups of 16 blocks (same bs), monotonic counter.
// Exchange: s goes through s_out (fp32) with AGENT-scope atomics (coherent at
// Infinity Cache) — NO threadfence, so L2 stays warm (no buffer_inv/wbl2).
// ---------------------------------------------------------------------------
__global__ __launch_bounds__(256, 1) void rnn_kernel(
    const float* __restrict__ X,    // [B][T][DIN]
    const float* __restrict__ W,    // [N][N]
    const float* __restrict__ Win,  // [DIN][N]
    float* __restrict__ s_out,      // [B][T][N]
    unsigned int* __restrict__ cnt) // 4 counters, 128B apart
{
    const int bs   = blockIdx.x & 3;
    const int cg   = blockIdx.x >> 2;
    const int tid  = threadIdx.x;
    const int wave = tid >> 6;
    const int lane = tid & 63;
    const int l15  = lane & 15;
    const int quad = lane >> 4;
    const int col0 = cg * 64 + wave * 16;   // wave's first col
    const int arow = bs * 16 + l15;         // A-frag batch row
    const int crow = bs * 16 + quad * 4;    // C-frag base batch row

    __shared__ _Float16 slab[16][1032];     // W/Win staging, then per-step s-slab

    // ---- one-time: W fragments (4 passes through shared slab)
    half8 wf[32];
    for (int w = 0; w < 4; ++w) {
        const int c = tid & 15, k0 = tid >> 4;
        const int wc = cg * 64 + w * 16 + c;
        #pragma unroll 4
        for (int k = k0; k < N_; k += 16)
            slab[c][k] = (_Float16)W[(size_t)k * N_ + wc];
        __syncthreads();
        if (wave == w) {
            #pragma unroll
            for (int kb = 0; kb < 32; ++kb)
                wf[kb] = *(const half8*)&slab[l15][kb * 32 + quad * 8];
        }
        __syncthreads();
    }
    // ---- one-time: Win fragments
    half8 winf[8];
    for (int w = 0; w < 4; ++w) {
        const int c = tid & 15, k0 = tid >> 4;
        const int wc = cg * 64 + w * 16 + c;
        for (int k = k0; k < DIN_; k += 16)
            slab[c][k] = (_Float16)Win[(size_t)k * N_ + wc];
        __syncthreads();
        if (wave == w) {
            #pragma unroll
            for (int kb = 0; kb < 8; ++kb)
                winf[kb] = *(const half8*)&slab[l15][kb * 32 + quad * 8];
        }
        __syncthreads();
    }

    // ---- s[:,0,:] = 0 for this block's 16r x 64c slice
    #pragma unroll
    for (int i = 0; i < 4; ++i) {
        int e = i * 256 + tid;
        int r = e >> 6, c = e & 63;
        s_out[(size_t)(bs * 16 + r) * T_ * N_ + cg * 64 + c] = 0.0f;
    }

    // ---- u_1 = X[:,0,:] @ Win
    f32x4 u = {0.f, 0.f, 0.f, 0.f};
    {
        const float* xp = X + (size_t)arow * T_ * DIN_ + quad * 8;
        #pragma unroll
        for (int kb = 0; kb < 8; ++kb) {
            float4 x0 = *(const float4*)(xp + kb * 32);
            float4 x1 = *(const float4*)(xp + kb * 32 + 4);
            u = __builtin_amdgcn_mfma_f32_16x16x32_f16(cvt8(x0, x1), winf[kb], u, 0, 0, 0);
        }
    }

    unsigned int* my_cnt = cnt + bs * 32;

    for (int t = 1; t < T_; ++t) {
        // prefetch X[:, t, :] for u_{t+1} (off critical path)
        float4 xpre[16];
        if (t < T_ - 1) {
            const float* xp = X + ((size_t)arow * T_ + t) * DIN_ + quad * 8;
            #pragma unroll
            for (int kb = 0; kb < 8; ++kb) {
                xpre[2 * kb]     = *(const float4*)(xp + kb * 32);
                xpre[2 * kb + 1] = *(const float4*)(xp + kb * 32 + 4);
            }
        }

        f32x4 acc[4];
        acc[0] = u;
        acc[1] = f32x4{0.f, 0.f, 0.f, 0.f};
        acc[2] = f32x4{0.f, 0.f, 0.f, 0.f};
        acc[3] = f32x4{0.f, 0.f, 0.f, 0.f};

        if (t >= 2) {
            // wait for the 16 blocks of this bs-group to have published s_{t-1}
            if (tid == 0) {
                const unsigned int target = (unsigned int)(t - 1) * 16u;
                while (__hip_atomic_load(my_cnt, __ATOMIC_RELAXED,
                                         __HIP_MEMORY_SCOPE_AGENT) < target) { }
            }
            __syncthreads();

            // stage s_{t-1}[bs-slab] (16 x 1024 fp32) -> fp16 LDS slab
            const float* srow = s_out + ((size_t)(bs * 16) * T_ + (t - 1)) * N_;
            #pragma unroll
            for (int i = 0; i < 32; ++i) {
                int g = i * 256 + tid;
                int r = g >> 9, kk = (g & 511) << 1;
                const float* p = srow + (size_t)r * T_ * N_ + kk;
                unsigned long long raw = __hip_atomic_load(
                    (unsigned long long*)p, __ATOMIC_RELAXED, __HIP_MEMORY_SCOPE_AGENT);
                float f0, f1;
                unsigned int lo = (unsigned int)raw, hi = (unsigned int)(raw >> 32);
                __builtin_memcpy(&f0, &lo, 4);
                __builtin_memcpy(&f1, &hi, 4);
                union { _Float16 h[2]; unsigned int u32; } pk;
                pk.h[0] = (_Float16)f0; pk.h[1] = (_Float16)f1;
                *(unsigned int*)&slab[r][kk] = pk.u32;
            }
            __syncthreads();

            #pragma unroll
            for (int kb = 0; kb < 32; ++kb) {
                half8 a = *(const half8*)&slab[l15][kb * 32 + quad * 8];
                acc[kb & 3] = __builtin_amdgcn_mfma_f32_16x16x32_f16(a, wf[kb], acc[kb & 3], 0, 0, 0);
            }
        }

        // u_{t+1} (independent chain)
        f32x4 un = {0.f, 0.f, 0.f, 0.f};
        if (t < T_ - 1) {
            #pragma unroll
            for (int kb = 0; kb < 8; ++kb)
                un = __builtin_amdgcn_mfma_f32_16x16x32_f16(
                        cvt8(xpre[2 * kb], xpre[2 * kb + 1]), winf[kb], un, 0, 0, 0);
        }

        float* so = s_out + ((size_t)crow * T_ + t) * N_ + col0 + l15;
        #pragma unroll
        for (int r = 0; r < 4; ++r) {
            float v = fast_tanh(acc[0][r] + acc[1][r] + acc[2][r] + acc[3][r]);
            __hip_atomic_store(so + (size_t)r * T_ * N_, v,
                               __ATOMIC_RELAXED, __HIP_MEMORY_SCOPE_AGENT);
        }
        u = un;

        // __syncthreads emits s_waitcnt vmcnt(0) per wave before s_barrier:
        // all 4 waves' write-through stores are at the coherence point after this.
        __syncthreads();
        if (tid == 0)
            __hip_atomic_fetch_add(my_cnt, 1u, __ATOMIC_RELAXED, __HIP_MEMORY_SCOPE_AGENT);
    }
}

// ---------------------------------------------------------------------------
// Epilogue: out = s @ Wout + bout.  M=32768, N=128, K=1024.
// 256 blocks x 256 threads; tile 128(M) x 128(N); Wout chunk fp16 in LDS.
// ---------------------------------------------------------------------------
__global__ __launch_bounds__(256, 2) void out_gemm(
    const float* __restrict__ s_in,   // [B*T][N]
    const float* __restrict__ Wout,   // [N][O]
    const float* __restrict__ bout,   // [O]
    float* __restrict__ outp)         // [B*T][O]
{
    const int m0   = blockIdx.x * 128;
    const int tid  = threadIdx.x;
    const int wave = tid >> 6;
    const int lane = tid & 63;
    const int l15  = lane & 15;
    const int quad = lane >> 4;

    __shared__ _Float16 WoT[128][40];   // pad: row = 40 halfs -> 2-way banks (free)

    f32x4 acc[2][8];
    #pragma unroll
    for (int mf = 0; mf < 2; ++mf)
        #pragma unroll
        for (int nt = 0; nt < 8; ++nt) acc[mf][nt] = f32x4{0.f, 0.f, 0.f, 0.f};
    float bv[8];
    #pragma unroll
    for (int nt = 0; nt < 8; ++nt) bv[nt] = bout[nt * 16 + l15];

    for (int kb = 0; kb < 32; ++kb) {
        __syncthreads();
        #pragma unroll
        for (int i = 0; i < 16; ++i) {
            int e = i * 256 + tid;
            int c = e & 127, kk = e >> 7;
            WoT[c][kk] = (_Float16)Wout[(size_t)(kb * 32 + kk) * O_ + c];
        }
        __syncthreads();

        #pragma unroll
        for (int mf = 0; mf < 2; ++mf) {
            const float* ap = s_in + (size_t)(m0 + wave * 32 + mf * 16 + l15) * N_ + kb * 32 + quad * 8;
            float4 a0 = *(const float4*)ap;
            float4 a1 = *(const float4*)(ap + 4);
            half8 a = cvt8(a0, a1);
            #pragma unroll
            for (int nt = 0; nt < 8; ++nt) {
                half8 b = *(const half8*)&WoT[nt * 16 + l15][quad * 8];
                acc[mf][nt] = __builtin_amdgcn_mfma_f32_16x16x32_f16(a, b, acc[mf][nt], 0, 0, 0);
            }
        }
    }

    #pragma unroll
    for (int mf = 0; mf < 2; ++mf) {
        float* op = outp + (size_t)(m0 + wave * 32 + mf * 16 + quad * 4) * O_ + l15;
        #pragma unroll
        for (int nt = 0; nt < 8; ++nt)
            #pragma unroll
            for (int r = 0; r < 4; ++r)
                op[(size_t)r * O_ + nt * 16] = acc[mf][nt][r] + bv[nt];
    }
}

extern "C" void kernel_launch(void* const* d_in, const int* in_sizes, int n_in,
                              void* d_out, int out_size, void* d_ws, size_t ws_size,
                              hipStream_t stream) {
    const float* X    = (const float*)d_in[0];   // [64][512][256]
    const float* Win  = (const float*)d_in[1];   // [256][1024]
    const float* W    = (const float*)d_in[2];   // [1024][1024]
    const float* Wout = (const float*)d_in[3];   // [1024][128]
    const float* bout = (const float*)d_in[4];   // [128]

    float* s_out = (float*)d_out;                 // [64][512][1024]
    float* outp  = s_out + (size_t)B_ * T_ * N_;  // [64][512][128]

    unsigned int* cnt = (unsigned int*)d_ws;      // 4 counters, 128 B apart

    init_kernel<<<1, 64, 0, stream>>>(cnt);
    rnn_kernel<<<64, 256, 0, stream>>>(X, W, Win, s_out, cnt);
    out_gemm<<<256, 256, 0, stream>>>(s_out, Wout, bout, outp);
}

// Round 4
// 3219.742 us; speedup vs baseline: 3.2363x; 1.8759x over previous
//
#include <hip/hip_runtime.h>

// Problem constants
#define B_ 64
#define T_ 512
#define DIN_ 256
#define N_ 1024
#define O_ 128

using half8 = __attribute__((ext_vector_type(8))) _Float16;
using f32x4 = __attribute__((ext_vector_type(4))) float;
typedef unsigned long long ull;

__device__ __forceinline__ half8 cvt8(float4 a, float4 b) {
    half8 h;
    h[0] = (_Float16)a.x; h[1] = (_Float16)a.y; h[2] = (_Float16)a.z; h[3] = (_Float16)a.w;
    h[4] = (_Float16)b.x; h[5] = (_Float16)b.y; h[6] = (_Float16)b.z; h[7] = (_Float16)b.w;
    return h;
}

__device__ __forceinline__ float fast_tanh(float x) {
    float ax = __builtin_fabsf(x);
    float e  = __expf(-2.0f * ax);
    float r  = __fdividef(1.0f - e, 1.0f + e);
    return x < 0.0f ? -r : r;
}

// ---------------------------------------------------------------------------
__global__ void init_kernel(unsigned int* flags) {
    if (threadIdx.x < 128) flags[threadIdx.x] = 0u;
}

// ---------------------------------------------------------------------------
// Persistent recurrence: 32 blocks = 4 batch-slabs (bs) x 8 col-groups (cg).
// Block = 512 threads (8 waves), 16 batch rows x 128 cols; wave w owns 16 cols
// with its W slab (128 VGPRs fp16) + Win slab (32 VGPRs) register-resident.
// Exchange: fp16 ping-pong buffer in MFMA A-FRAGMENT order (addr_half =
// kb*512 + lane*8 + j). Consumer staging: 8 batched 8B agent-scope atomic
// loads/thread (32768 B = full 16x1024 fp16 slab — R2 bug was staging only
// half) -> linear LDS writes (2-way bank aliasing, free) -> ds_read_b128 at
// lane*16B (conflict-free). Sync: per-block flag stores, polled by all waves
// with one coalesced 32B load (lanes 0-7). s_out fp32 stores + u_{t+1}
// input-GEMM happen AFTER publish (off critical path).
// ---------------------------------------------------------------------------
__global__ __launch_bounds__(512, 1) void rnn_kernel(
    const float* __restrict__ X,      // [B][T][DIN]
    const float* __restrict__ W,      // [N][N]
    const float* __restrict__ Win,    // [DIN][N]
    float* __restrict__ s_out,        // [B][T][N]
    _Float16* __restrict__ exch,      // [4][2][16384] fp16, frag order
    unsigned int* __restrict__ flags) // [4][32], first 8 used per group
{
    const int bs   = blockIdx.x & 3;
    const int cg   = blockIdx.x >> 2;     // 0..7
    const int tid  = threadIdx.x;
    const int wave = tid >> 6;            // 0..7
    const int lane = tid & 63;
    const int l15  = lane & 15;
    const int quad = lane >> 4;
    const int col0 = cg * 128 + wave * 16;
    const int arow = bs * 16 + l15;       // A-frag batch row
    const int crow = bs * 16 + quad * 4;  // C-frag base batch row

    __shared__ _Float16 slab[16 * 1032];  // W/Win transpose staging + step slab

    // ---- one-time: W B-fragments (8 passes, one per wave)
    half8 wf[32];
    for (int p = 0; p < 8; ++p) {
        const int c = tid & 15, k0 = tid >> 4;
        const int wc = cg * 128 + p * 16 + c;
        for (int k = k0; k < N_; k += 32)
            slab[c * 1032 + k] = (_Float16)W[(size_t)k * N_ + wc];
        __syncthreads();
        if (wave == p) {
            #pragma unroll
            for (int kb = 0; kb < 32; ++kb)
                wf[kb] = *(const half8*)&slab[l15 * 1032 + kb * 32 + quad * 8];
        }
        __syncthreads();
    }
    // ---- one-time: Win B-fragments
    half8 winf[8];
    for (int p = 0; p < 8; ++p) {
        const int c = tid & 15, k0 = tid >> 4;
        const int wc = cg * 128 + p * 16 + c;
        for (int k = k0; k < DIN_; k += 32)
            slab[c * 1032 + k] = (_Float16)Win[(size_t)k * N_ + wc];
        __syncthreads();
        if (wave == p) {
            #pragma unroll
            for (int kb = 0; kb < 8; ++kb)
                winf[kb] = *(const half8*)&slab[l15 * 1032 + kb * 32 + quad * 8];
        }
        __syncthreads();
    }

    // ---- s[:,0,:] = 0 for this block's 16r x 128c slice
    #pragma unroll
    for (int i = 0; i < 4; ++i) {
        int e = i * 512 + tid;
        int r = e >> 7, c = e & 127;
        s_out[(size_t)(bs * 16 + r) * T_ * N_ + cg * 128 + c] = 0.0f;
    }

    // ---- u_1 = X[:,0,:] @ Win
    f32x4 u = {0.f, 0.f, 0.f, 0.f};
    {
        const float* xp = X + (size_t)arow * T_ * DIN_ + quad * 8;
        #pragma unroll
        for (int kb = 0; kb < 8; ++kb) {
            float4 x0 = *(const float4*)(xp + kb * 32);
            float4 x1 = *(const float4*)(xp + kb * 32 + 4);
            u = __builtin_amdgcn_mfma_f32_16x16x32_f16(cvt8(x0, x1), winf[kb], u, 0, 0, 0);
        }
    }

    // producer exchange address (frag order): element (m=row, col):
    // addr_half = (col>>5)*512 + ((col>>3)&3)*128 + m*8 + (col&7); m = quad*4+r
    const int col   = col0 + l15;
    const int ebase = (col >> 5) * 512 + ((col >> 3) & 3) * 128 + quad * 32 + (col & 7);

    unsigned int* fl = flags + bs * 32;

    for (int t = 1; t < T_; ++t) {
        f32x4 acc0 = u;
        f32x4 acc1 = {0.f, 0.f, 0.f, 0.f};
        f32x4 acc2 = {0.f, 0.f, 0.f, 0.f};
        f32x4 acc3 = {0.f, 0.f, 0.f, 0.f};

        if (t >= 2) {
            const unsigned int tgt = (unsigned int)(t - 1);
            // all waves poll: one coalesced 32B load per iteration (lanes 0-7)
            for (;;) {
                unsigned int v = tgt;
                if (lane < 8)
                    v = __hip_atomic_load(&fl[lane], __ATOMIC_RELAXED, __HIP_MEMORY_SCOPE_AGENT);
                if (__all((int)(v >= tgt))) break;
            }

            // batched stage: 8 x 8B agent atomic loads -> linear LDS writes
            // (full 4096-ull slab; 512 threads x 8)
            const ull* ep = (const ull*)(exch + (size_t)(bs * 2 + ((t - 1) & 1)) * 16384);
            ull r0 = __hip_atomic_load(&ep[tid],        __ATOMIC_RELAXED, __HIP_MEMORY_SCOPE_AGENT);
            ull r1 = __hip_atomic_load(&ep[tid + 512],  __ATOMIC_RELAXED, __HIP_MEMORY_SCOPE_AGENT);
            ull r2 = __hip_atomic_load(&ep[tid + 1024], __ATOMIC_RELAXED, __HIP_MEMORY_SCOPE_AGENT);
            ull r3 = __hip_atomic_load(&ep[tid + 1536], __ATOMIC_RELAXED, __HIP_MEMORY_SCOPE_AGENT);
            ull r4 = __hip_atomic_load(&ep[tid + 2048], __ATOMIC_RELAXED, __HIP_MEMORY_SCOPE_AGENT);
            ull r5 = __hip_atomic_load(&ep[tid + 2560], __ATOMIC_RELAXED, __HIP_MEMORY_SCOPE_AGENT);
            ull r6 = __hip_atomic_load(&ep[tid + 3072], __ATOMIC_RELAXED, __HIP_MEMORY_SCOPE_AGENT);
            ull r7 = __hip_atomic_load(&ep[tid + 3584], __ATOMIC_RELAXED, __HIP_MEMORY_SCOPE_AGENT);
            ull* lp = (ull*)slab;
            lp[tid]        = r0;
            lp[tid + 512]  = r1;
            lp[tid + 1024] = r2;
            lp[tid + 1536] = r3;
            lp[tid + 2048] = r4;
            lp[tid + 2560] = r5;
            lp[tid + 3072] = r6;
            lp[tid + 3584] = r7;
            __syncthreads();

            #pragma unroll
            for (int kb = 0; kb < 32; ++kb) {
                half8 a = *(const half8*)&slab[kb * 512 + lane * 8];
                if ((kb & 3) == 0)      acc0 = __builtin_amdgcn_mfma_f32_16x16x32_f16(a, wf[kb], acc0, 0, 0, 0);
                else if ((kb & 3) == 1) acc1 = __builtin_amdgcn_mfma_f32_16x16x32_f16(a, wf[kb], acc1, 0, 0, 0);
                else if ((kb & 3) == 2) acc2 = __builtin_amdgcn_mfma_f32_16x16x32_f16(a, wf[kb], acc2, 0, 0, 0);
                else                    acc3 = __builtin_amdgcn_mfma_f32_16x16x32_f16(a, wf[kb], acc3, 0, 0, 0);
            }
        }

        float v4[4];
        #pragma unroll
        for (int r = 0; r < 4; ++r)
            v4[r] = fast_tanh(acc0[r] + acc1[r] + acc2[r] + acc3[r]);

        // critical-path publish: fp16 frag-order exchange stores
        _Float16* eb = exch + (size_t)(bs * 2 + (t & 1)) * 16384;
        #pragma unroll
        for (int r = 0; r < 4; ++r) {
            union { _Float16 h; unsigned short s; } cv;
            cv.h = (_Float16)v4[r];
            __hip_atomic_store((unsigned short*)(eb + ebase + r * 8), cv.s,
                               __ATOMIC_RELAXED, __HIP_MEMORY_SCOPE_AGENT);
        }
        __syncthreads();   // drains all waves' exch stores (vmcnt 0)
        if (tid == 0)
            __hip_atomic_store(&fl[cg], (unsigned int)t,
                               __ATOMIC_RELAXED, __HIP_MEMORY_SCOPE_AGENT);

        // ---- off critical path: fp32 s_out + u_{t+1}
        #pragma unroll
        for (int r = 0; r < 4; ++r)
            s_out[(size_t)(crow + r) * T_ * N_ + (size_t)t * N_ + col] = v4[r];

        f32x4 un = {0.f, 0.f, 0.f, 0.f};
        if (t < T_ - 1) {
            const float* xp = X + ((size_t)arow * T_ + t) * DIN_ + quad * 8;
            #pragma unroll
            for (int kb = 0; kb < 8; ++kb) {
                float4 x0 = *(const float4*)(xp + kb * 32);
                float4 x1 = *(const float4*)(xp + kb * 32 + 4);
                un = __builtin_amdgcn_mfma_f32_16x16x32_f16(cvt8(x0, x1), winf[kb], un, 0, 0, 0);
            }
        }
        u = un;
    }
}

// ---------------------------------------------------------------------------
// Epilogue: out = s @ Wout + bout.  M=32768, N=128, K=1024.
// ---------------------------------------------------------------------------
__global__ __launch_bounds__(256, 2) void out_gemm(
    const float* __restrict__ s_in,   // [B*T][N]
    const float* __restrict__ Wout,   // [N][O]
    const float* __restrict__ bout,   // [O]
    float* __restrict__ outp)         // [B*T][O]
{
    const int m0   = blockIdx.x * 128;
    const int tid  = threadIdx.x;
    const int wave = tid >> 6;
    const int lane = tid & 63;
    const int l15  = lane & 15;
    const int quad = lane >> 4;

    __shared__ _Float16 WoT[128][40];

    f32x4 acc[2][8];
    #pragma unroll
    for (int mf = 0; mf < 2; ++mf)
        #pragma unroll
        for (int nt = 0; nt < 8; ++nt) acc[mf][nt] = f32x4{0.f, 0.f, 0.f, 0.f};
    float bv[8];
    #pragma unroll
    for (int nt = 0; nt < 8; ++nt) bv[nt] = bout[nt * 16 + l15];

    for (int kb = 0; kb < 32; ++kb) {
        __syncthreads();
        #pragma unroll
        for (int i = 0; i < 16; ++i) {
            int e = i * 256 + tid;
            int c = e & 127, kk = e >> 7;
            WoT[c][kk] = (_Float16)Wout[(size_t)(kb * 32 + kk) * O_ + c];
        }
        __syncthreads();

        #pragma unroll
        for (int mf = 0; mf < 2; ++mf) {
            const float* ap = s_in + (size_t)(m0 + wave * 32 + mf * 16 + l15) * N_ + kb * 32 + quad * 8;
            float4 a0 = *(const float4*)ap;
            float4 a1 = *(const float4*)(ap + 4);
            half8 a = cvt8(a0, a1);
            #pragma unroll
            for (int nt = 0; nt < 8; ++nt) {
                half8 b = *(const half8*)&WoT[nt * 16 + l15][quad * 8];
                acc[mf][nt] = __builtin_amdgcn_mfma_f32_16x16x32_f16(a, b, acc[mf][nt], 0, 0, 0);
            }
        }
    }

    #pragma unroll
    for (int mf = 0; mf < 2; ++mf) {
        float* op = outp + (size_t)(m0 + wave * 32 + mf * 16 + quad * 4) * O_ + l15;
        #pragma unroll
        for (int nt = 0; nt < 8; ++nt)
            #pragma unroll
            for (int r = 0; r < 4; ++r)
                op[(size_t)r * O_ + nt * 16] = acc[mf][nt][r] + bv[nt];
    }
}

extern "C" void kernel_launch(void* const* d_in, const int* in_sizes, int n_in,
                              void* d_out, int out_size, void* d_ws, size_t ws_size,
                              hipStream_t stream) {
    const float* X    = (const float*)d_in[0];   // [64][512][256]
    const float* Win  = (const float*)d_in[1];   // [256][1024]
    const float* W    = (const float*)d_in[2];   // [1024][1024]
    const float* Wout = (const float*)d_in[3];   // [1024][128]
    const float* bout = (const float*)d_in[4];   // [128]

    float* s_out = (float*)d_out;                 // [64][512][1024]
    float* outp  = s_out + (size_t)B_ * T_ * N_;  // [64][512][128]

    unsigned int* flags = (unsigned int*)d_ws;             // 128 uints
    _Float16* exch = (_Float16*)((char*)d_ws + 1024);      // 256 KB

    init_kernel<<<1, 128, 0, stream>>>(flags);
    rnn_kernel<<<32, 512, 0, stream>>>(X, W, Win, s_out, exch, flags);
    out_gemm<<<256, 256, 0, stream>>>(s_out, Wout, bout, outp);
}